// Round 14
// baseline (138.642 us; speedup 1.0000x reference)
//
#include <hip/hip_runtime.h>
#include <hip/hip_bf16.h>

typedef unsigned short u16;
typedef __attribute__((ext_vector_type(4))) float f32x4;
typedef __attribute__((ext_vector_type(16))) float f32x16;
typedef __attribute__((ext_vector_type(8))) short short8;
typedef __attribute__((ext_vector_type(8))) unsigned short ushort8;

#define AS1 __attribute__((address_space(1)))
#define AS3 __attribute__((address_space(3)))

__device__ __forceinline__ u16 f2bf(float f) {
  union { float f; unsigned u; } v; v.f = f;
  unsigned r = v.u + 0x7fffu + ((v.u >> 16) & 1u);
  return (u16)(r >> 16);
}
__device__ __forceinline__ float b2f(u16 h) {
  union { unsigned u; float f; } v; v.u = ((unsigned)h) << 16;
  return v.f;
}
__device__ __forceinline__ f32x4 mfma16(short8 a, short8 b, f32x4 c) {
  return __builtin_amdgcn_mfma_f32_16x16x32_bf16(a, b, c, 0, 0, 0);
}
__device__ __forceinline__ f32x16 mfma32(short8 a, short8 b, f32x16 c) {
  return __builtin_amdgcn_mfma_f32_32x32x16_bf16(a, b, c, 0, 0, 0);
}
__device__ __forceinline__ unsigned cvtpk(float a, float b) {
  unsigned r;
  asm("v_cvt_pk_bf16_f32 %0, %1, %2" : "=v"(r) : "v"(a), "v"(b));
  return r;
}
__device__ __forceinline__ short8 pack4(unsigned w0, unsigned w1, unsigned w2, unsigned w3) {
  union { unsigned u[4]; short8 s; } t;
  t.u[0] = w0; t.u[1] = w1; t.u[2] = w2; t.u[3] = w3;
  return t.s;
}
__device__ __forceinline__ float exp2h(float x) { return __builtin_amdgcn_exp2f(x); }

// ---------------- prep: fp32 -> bf16 convert ----------------
__global__ __launch_bounds__(256) void cvt_f32_bf16_k(const float* __restrict__ in,
                                                      u16* __restrict__ out, int n8) {
  int t = blockIdx.x * 256 + threadIdx.x;
  if (t >= n8) return;
  const float4* p = (const float4*)(in + (size_t)t * 8);
  float4 a = p[0], b = p[1];
  ushort8 o;
  o[0] = f2bf(a.x); o[1] = f2bf(a.y); o[2] = f2bf(a.z); o[3] = f2bf(a.w);
  o[4] = f2bf(b.x); o[5] = f2bf(b.y); o[6] = f2bf(b.z); o[7] = f2bf(b.w);
  *(ushort8*)(out + (size_t)t * 8) = o;
}

// ---------------- prep: transpose fp32 [R][C] -> bf16 [C][R] ----------------
__global__ __launch_bounds__(256) void transpose_f32_bf16_k(const float* __restrict__ in,
                                                            u16* __restrict__ out, int R, int C) {
  __shared__ float tile[32][33];
  int bc = blockIdx.x * 32, br = blockIdx.y * 32;
  int tx = threadIdx.x & 31, ty = threadIdx.x >> 5;
#pragma unroll
  for (int p = 0; p < 4; ++p)
    tile[ty + p * 8][tx] = in[(size_t)(br + ty + p * 8) * C + bc + tx];
  __syncthreads();
#pragma unroll
  for (int p = 0; p < 4; ++p)
    out[(size_t)(bc + ty + p * 8) * R + br + tx] = f2bf(tile[tx][ty + p * 8]);
}

// ---------------- GEMM (m97 structure): C = A * Bt^T, K=1024, BK=32 ----------
// MODE 0: qkv epilogue: bias + fused RoPE (Q pre-scaled) -> NATURAL [4096][3072] bf16 layout
//         (coalesced row-major u16 stores; consumers are stride-aware).
// MODE 1: out epilogue (bias + fp32 store [m][1024]).
template <int MODE>
__global__ __launch_bounds__(256) void gemm_bt_k(const u16* __restrict__ A,
                                                 const u16* __restrict__ Bt,
                                                 const float* __restrict__ bias,
                                                 const float* __restrict__ cosT,
                                                 const float* __restrict__ sinT,
                                                 void* __restrict__ Cout) {
  __shared__ __align__(16) u16 As[128 * 32];
  __shared__ __align__(16) u16 Bs[128 * 32];
  const int tid = threadIdx.x, lane = tid & 63, w = tid >> 6;
  const int wr = w >> 1, wc = w & 1, g = lane >> 4, c16 = lane & 15;
  const int rowBase = blockIdx.y * 128, colBase = blockIdx.x * 128;
  f32x4 acc[4][4] = {};
  const int e0 = (w * 2 + 0) * 512 + lane * 8;
  const int e1 = (w * 2 + 1) * 512 + lane * 8;
  const u16* Ag0 = A + (size_t)(rowBase + (e0 >> 5)) * 1024 + (e0 & 31);
  const u16* Ag1 = A + (size_t)(rowBase + (e1 >> 5)) * 1024 + (e1 & 31);
  const u16* Bg0 = Bt + (size_t)(colBase + (e0 >> 5)) * 1024 + (e0 & 31);
  const u16* Bg1 = Bt + (size_t)(colBase + (e1 >> 5)) * 1024 + (e1 & 31);
  u16* As0 = As + (w * 2 + 0) * 512;
  u16* As1 = As + (w * 2 + 1) * 512;
  u16* Bs0 = Bs + (w * 2 + 0) * 512;
  u16* Bs1 = Bs + (w * 2 + 1) * 512;
  for (int k0 = 0; k0 < 1024; k0 += 32) {
    __builtin_amdgcn_global_load_lds((const AS1 void*)(Ag0 + k0), (AS3 void*)As0, 16, 0, 0);
    __builtin_amdgcn_global_load_lds((const AS1 void*)(Ag1 + k0), (AS3 void*)As1, 16, 0, 0);
    __builtin_amdgcn_global_load_lds((const AS1 void*)(Bg0 + k0), (AS3 void*)Bs0, 16, 0, 0);
    __builtin_amdgcn_global_load_lds((const AS1 void*)(Bg1 + k0), (AS3 void*)Bs1, 16, 0, 0);
    asm volatile("s_waitcnt vmcnt(0)" ::: "memory");
    __syncthreads();
    short8 af[4], bfr[4];
#pragma unroll
    for (int t = 0; t < 4; ++t)
      af[t] = *(const short8*)(As + ((wr * 64 + t * 16 + c16) * 32 + g * 8));
#pragma unroll
    for (int t = 0; t < 4; ++t)
      bfr[t] = *(const short8*)(Bs + ((wc * 64 + t * 16 + c16) * 32 + g * 8));
#pragma unroll
    for (int i = 0; i < 4; ++i)
#pragma unroll
      for (int j = 0; j < 4; ++j) acc[i][j] = mfma16(af[i], bfr[j], acc[i][j]);
    __syncthreads();
  }
#pragma unroll
  for (int i = 0; i < 4; ++i) {
    int mbase = rowBase + wr * 64 + i * 16 + 4 * g;
#pragma unroll
    for (int j = 0; j < 4; ++j) {
      int n = colBase + wc * 64 + j * 16 + c16;
      float bv = bias[n];
      const int which = n >> 10, d = n & 63;
#pragma unroll
      for (int r = 0; r < 4; ++r) {
        float v = acc[i][j][r] + bv;
        int m = mbase + r;
        if (MODE == 0) {
          const int s = m & 2047;
          float outv = v;
          if (which < 2) {  // fused RoPE (pair element lives in lane^1, same i,j,r)
            float pv = __shfl_xor(v, 1);
            float cc = cosT[(size_t)s * 32 + (d >> 1)];
            float ss = sinT[(size_t)s * 32 + (d >> 1)];
            outv = (d & 1) ? (v * cc + pv * ss) : (v * cc - pv * ss);
            if (which == 0) outv *= 0.18033688f;  // 0.125 * log2(e)
          }
          ((u16*)Cout)[(size_t)m * 3072 + n] = f2bf(outv);   // natural layout, coalesced
        } else {
          ((float*)Cout)[(size_t)m * 1024 + n] = v;
        }
      }
    }
  }
}

// ---------------- V (cols 2048..3071 of QKVn, stride 3072) -> Vt [bh][64][2048] ----------------
__global__ __launch_bounds__(256) void vtrans_k(const u16* __restrict__ QKVn, u16* __restrict__ Vt) {
  __shared__ u16 t[64][72];
  const int bh = blockIdx.y, s0 = blockIdx.x * 64;
  const int b = bh >> 4, h = bh & 15;
  const u16* src = QKVn + (size_t)b * 2048 * 3072 + 2048 + h * 64;   // row stride 3072
  u16* dst = Vt + ((size_t)bh << 17);
  const int r = threadIdx.x >> 2, c0 = (threadIdx.x & 3) * 16;
  *(short8*)&t[r][c0] = *(const short8*)(src + (size_t)(s0 + r) * 3072 + c0);
  *(short8*)&t[r][c0 + 8] = *(const short8*)(src + (size_t)(s0 + r) * 3072 + c0 + 8);
  __syncthreads();
  const int d = threadIdx.x >> 2, sc0 = (threadIdx.x & 3) * 16;
  ushort8 o0, o1;
#pragma unroll
  for (int e = 0; e < 8; ++e) { o0[e] = t[sc0 + e][d]; o1[e] = t[sc0 + 8 + e][d]; }
  *(ushort8*)(dst + (size_t)d * 2048 + s0 + sc0) = o0;
  *(ushort8*)(dst + (size_t)d * 2048 + s0 + sc0 + 8) = o1;
}

// ---------------- Flash attention v7 (best structure), stride-aware Q/K (3072) ----------------
__global__ __launch_bounds__(256, 2) void attn7_k(const u16* __restrict__ QKVn,
                                                  const u16* __restrict__ Vtm,
                                                  u16* __restrict__ Om) {
  __shared__ __align__(16) u16 KL[2][4096];
  __shared__ __align__(16) u16 VL[2][4096];

  const int tid = threadIdx.x;
  const int lane = tid & 63, w = tid >> 6;
  const int x = blockIdx.x & 7;
  const int i = blockIdx.x >> 3;
  const int bh = 4 * x + (i & 3);
  const int rank = i >> 2;
  const int qm = (rank < 8) ? (15 - rank) : (rank - 8);
  const int b = bh >> 4, hd = bh & 15;
  const int qb = qm * 128 + w * 32;
  const int q32 = lane & 31, hl = lane >> 5;
  const int nt = 2 * qm + 2;

  const u16* Qp = QKVn + (size_t)b * 2048 * 3072 + hd * 64;   // row stride 3072
  const u16* Kp = Qp + 1024;
  const u16* Vtp = Vtm + ((size_t)bh << 17);

  const u16* qrow = Qp + (size_t)(qb + q32) * 3072 + 8 * hl;
  short8 qf[4];
#pragma unroll
  for (int ks = 0; ks < 4; ++ks) qf[ks] = *(const short8*)(qrow + 16 * ks);

  f32x16 acc0 = {}, acc1 = {};
  float m_run = -1e30f, l_run = 0.f;
  const int qg = qb + q32;
  const int rr = w * 8 + (lane >> 3);
  const int sb = (lane & 7) ^ (lane >> 3);
  const int swz = q32 & 7;

  auto stage = [&](int buf, int k0s) {
    u16* kb = &KL[buf][w * 512];
    u16* vb = &VL[buf][w * 512];
    __builtin_amdgcn_global_load_lds(
        (const AS1 void*)(Kp + (size_t)(k0s + rr) * 3072 + sb * 8),
        (AS3 void*)kb, 16, 0, 0);
    __builtin_amdgcn_global_load_lds(
        (const AS1 void*)(Kp + (size_t)(k0s + rr + 32) * 3072 + sb * 8),
        (AS3 void*)(kb + 2048), 16, 0, 0);
    __builtin_amdgcn_global_load_lds(
        (const AS1 void*)(Vtp + ((size_t)rr << 11) + k0s + sb * 8),
        (AS3 void*)vb, 16, 0, 0);
    __builtin_amdgcn_global_load_lds(
        (const AS1 void*)(Vtp + ((size_t)(rr + 32) << 11) + k0s + sb * 8),
        (AS3 void*)(vb + 2048), 16, 0, 0);
  };

  stage(0, 0);
  asm volatile("s_waitcnt vmcnt(0)" ::: "memory");
  __syncthreads();

  for (int it = 0; it < nt; ++it) {
    const int cur = it & 1;
    if (it + 1 < nt) stage(cur ^ 1, 64 * (it + 1));
    const int k0 = 64 * it;

    if (k0 <= qb + 31) {
      const u16* Kb = &KL[cur][0];
      const u16* Vb = &VL[cur][0];

      f32x16 s0 = {}, s1 = {};
      __builtin_amdgcn_s_setprio(1);
#pragma unroll
      for (int ks = 0; ks < 4; ++ks) {
        const int cb = ((2 * ks + hl) ^ swz) * 8;
        short8 kf0 = *(const short8*)(Kb + q32 * 64 + cb);
        short8 kf1 = *(const short8*)(Kb + (32 + q32) * 64 + cb);
        s0 = mfma32(kf0, qf[ks], s0);
        s1 = mfma32(kf1, qf[ks], s1);
      }
      __builtin_amdgcn_s_setprio(0);

      short8 vfa[4], vfb[4];
#pragma unroll
      for (int ks = 0; ks < 4; ++ks) {
        const int cb = ((2 * ks + hl) ^ swz) * 8;
        vfa[ks] = *(const short8*)(Vb + q32 * 64 + cb);
        vfb[ks] = *(const short8*)(Vb + (32 + q32) * 64 + cb);
      }

      if (k0 + 63 > qb) {
#pragma unroll
        for (int r = 0; r < 16; ++r) {
          const int kvl = k0 + (r & 3) + 8 * (r >> 2) + 4 * hl;
          s0[r] = (kvl <= qg) ? s0[r] : -1e30f;
          s1[r] = (kvl + 32 <= qg) ? s1[r] : -1e30f;
        }
      }

      float pmax = s0[0];
#pragma unroll
      for (int r = 1; r < 16; ++r) pmax = fmaxf(pmax, s0[r]);
#pragma unroll
      for (int r = 0; r < 16; ++r) pmax = fmaxf(pmax, s1[r]);
      pmax = fmaxf(pmax, __shfl_xor(pmax, 32));

      if (!__all(pmax <= m_run + 11.5f)) {
        const float mn = fmaxf(m_run, pmax);
        const float alpha = exp2h(m_run - mn);
        l_run *= alpha;
        m_run = mn;
#pragma unroll
        for (int r = 0; r < 16; ++r) {
          const int row = (r & 3) + 8 * (r >> 2) + 4 * hl;
          const float ar = __shfl(alpha, row);
          acc0[r] *= ar; acc1[r] *= ar;
        }
      }

      float rs = 0.f;
#pragma unroll
      for (int r = 0; r < 16; ++r) { s0[r] = exp2h(s0[r] - m_run); rs += s0[r]; }
#pragma unroll
      for (int r = 0; r < 16; ++r) { s1[r] = exp2h(s1[r] - m_run); rs += s1[r]; }
      rs += __shfl_xor(rs, 32);
      l_run += rs;

      short8 pa[4];
#pragma unroll
      for (int t = 0; t < 2; ++t) {
        float p0, p1, p2, p3, p4, p5, p6, p7, p8, p9, pa_, pb_, pc_, pd_, pe_, pf_;
        if (t == 0) {
          p0 = s0[0];  p1 = s0[1];  p2 = s0[2];  p3 = s0[3];
          p4 = s0[4];  p5 = s0[5];  p6 = s0[6];  p7 = s0[7];
          p8 = s0[8];  p9 = s0[9];  pa_ = s0[10]; pb_ = s0[11];
          pc_ = s0[12]; pd_ = s0[13]; pe_ = s0[14]; pf_ = s0[15];
        } else {
          p0 = s1[0];  p1 = s1[1];  p2 = s1[2];  p3 = s1[3];
          p4 = s1[4];  p5 = s1[5];  p6 = s1[6];  p7 = s1[7];
          p8 = s1[8];  p9 = s1[9];  pa_ = s1[10]; pb_ = s1[11];
          pc_ = s1[12]; pd_ = s1[13]; pe_ = s1[14]; pf_ = s1[15];
        }
        const unsigned a0 = cvtpk(p0, p1), a1 = cvtpk(p2, p3);
        const unsigned a2 = cvtpk(p4, p5), a3 = cvtpk(p6, p7);
        const unsigned b0 = cvtpk(p8, p9), b1 = cvtpk(pa_, pb_);
        const unsigned b2 = cvtpk(pc_, pd_), b3 = cvtpk(pe_, pf_);
        const unsigned r0 = __shfl_xor(hl ? a0 : a2, 32);
        const unsigned r1 = __shfl_xor(hl ? a1 : a3, 32);
        pa[2 * t] = hl ? pack4(r0, r1, a2, a3) : pack4(a0, a1, r0, r1);
        const unsigned r2 = __shfl_xor(hl ? b0 : b2, 32);
        const unsigned r3 = __shfl_xor(hl ? b1 : b3, 32);
        pa[2 * t + 1] = hl ? pack4(r2, r3, b2, b3) : pack4(b0, b1, r2, r3);
      }

      __builtin_amdgcn_s_setprio(1);
#pragma unroll
      for (int ks = 0; ks < 4; ++ks) {
        acc0 = mfma32(pa[ks], vfa[ks], acc0);
        acc1 = mfma32(pa[ks], vfb[ks], acc1);
      }
      __builtin_amdgcn_s_setprio(0);
    }

    asm volatile("s_waitcnt vmcnt(0)" ::: "memory");
    __syncthreads();
  }

#pragma unroll
  for (int r = 0; r < 16; ++r) {
    const int row = (r & 3) + 8 * (r >> 2) + 4 * hl;
    const float li = 1.0f / __shfl(l_run, row);
    const int q = qb + row;
    const size_t base = ((size_t)(b * 2048 + q) << 10) + hd * 64 + q32;
    Om[base] = f2bf(acc0[r] * li);
    Om[base + 32] = f2bf(acc1[r] * li);
  }
}

extern "C" void kernel_launch(void* const* d_in, const int* in_sizes, int n_in,
                              void* d_out, int out_size, void* d_ws, size_t ws_size,
                              hipStream_t stream) {
  const float* x        = (const float*)d_in[0];
  const float* rope_cos = (const float*)d_in[1];
  const float* rope_sin = (const float*)d_in[2];
  const float* Wqkv     = (const float*)d_in[3];
  const float* bqkv     = (const float*)d_in[4];
  const float* Wout     = (const float*)d_in[5];
  const float* bout     = (const float*)d_in[6];
  float* out = (float*)d_out;
  char* ws = (char*)d_ws;

  u16* Xb      = (u16*)(ws);                  //  8,388,608 B : x bf16 [4096][1024]
  u16* WqkvT   = (u16*)(ws + 8388608);        //  6,291,456 B : Wqkv^T bf16
  u16* WoutT   = (u16*)(ws + 14680064);       //  2,097,152 B : Wout^T bf16
  u16* QKVn    = (u16*)(ws + 16777216);       // 25,165,824 B : [4096][3072] bf16 natural
  u16* AttnOut = (u16*)(ws + 41943040);       //  8,388,608 B : [4096][1024] bf16
  u16* Vt      = (u16*)(ws + 50331648);       //  8,388,608 B : [32][64][2048] bf16

  cvt_f32_bf16_k<<<dim3(2048), dim3(256), 0, stream>>>(x, Xb, 524288);
  transpose_f32_bf16_k<<<dim3(96, 32), dim3(256), 0, stream>>>(Wqkv, WqkvT, 1024, 3072);
  transpose_f32_bf16_k<<<dim3(32, 32), dim3(256), 0, stream>>>(Wout, WoutT, 1024, 1024);

  // QKV projection: bias + RoPE + Q pre-scale fused, NATURAL layout out (coalesced stores)
  gemm_bt_k<0><<<dim3(24, 32), dim3(256), 0, stream>>>(Xb, WqkvT, bqkv, rope_cos, rope_sin,
                                                       (void*)QKVn);

  vtrans_k<<<dim3(32, 32), dim3(256), 0, stream>>>(QKVn, Vt);
  attn7_k<<<dim3(512), dim3(256), 0, stream>>>(QKVn, Vt, AttnOut);

  gemm_bt_k<1><<<dim3(8, 32), dim3(256), 0, stream>>>(AttnOut, WoutT, bout, nullptr, nullptr, out);
}

// Round 15
// 128.520 us; speedup vs baseline: 1.0788x; 1.0788x over previous
//
#include <hip/hip_runtime.h>
#include <hip/hip_bf16.h>

typedef unsigned short u16;
typedef __attribute__((ext_vector_type(4))) float f32x4;
typedef __attribute__((ext_vector_type(16))) float f32x16;
typedef __attribute__((ext_vector_type(8))) short short8;
typedef __attribute__((ext_vector_type(8))) unsigned short ushort8;

#define AS1 __attribute__((address_space(1)))
#define AS3 __attribute__((address_space(3)))

__device__ __forceinline__ u16 f2bf(float f) {
  union { float f; unsigned u; } v; v.f = f;
  unsigned r = v.u + 0x7fffu + ((v.u >> 16) & 1u);
  return (u16)(r >> 16);
}
__device__ __forceinline__ float b2f(u16 h) {
  union { unsigned u; float f; } v; v.u = ((unsigned)h) << 16;
  return v.f;
}
__device__ __forceinline__ f32x4 mfma16(short8 a, short8 b, f32x4 c) {
  return __builtin_amdgcn_mfma_f32_16x16x32_bf16(a, b, c, 0, 0, 0);
}
__device__ __forceinline__ f32x16 mfma32(short8 a, short8 b, f32x16 c) {
  return __builtin_amdgcn_mfma_f32_32x32x16_bf16(a, b, c, 0, 0, 0);
}
__device__ __forceinline__ unsigned cvtpk(float a, float b) {
  unsigned r;
  asm("v_cvt_pk_bf16_f32 %0, %1, %2" : "=v"(r) : "v"(a), "v"(b));
  return r;
}
__device__ __forceinline__ short8 pack4(unsigned w0, unsigned w1, unsigned w2, unsigned w3) {
  union { unsigned u[4]; short8 s; } t;
  t.u[0] = w0; t.u[1] = w1; t.u[2] = w2; t.u[3] = w3;
  return t.s;
}
__device__ __forceinline__ float exp2h(float x) { return __builtin_amdgcn_exp2f(x); }

// ---------------- prep: fp32 -> bf16 convert ----------------
__global__ __launch_bounds__(256) void cvt_f32_bf16_k(const float* __restrict__ in,
                                                      u16* __restrict__ out, int n8) {
  int t = blockIdx.x * 256 + threadIdx.x;
  if (t >= n8) return;
  const float4* p = (const float4*)(in + (size_t)t * 8);
  float4 a = p[0], b = p[1];
  ushort8 o;
  o[0] = f2bf(a.x); o[1] = f2bf(a.y); o[2] = f2bf(a.z); o[3] = f2bf(a.w);
  o[4] = f2bf(b.x); o[5] = f2bf(b.y); o[6] = f2bf(b.z); o[7] = f2bf(b.w);
  *(ushort8*)(out + (size_t)t * 8) = o;
}

// ---------------- prep: transpose fp32 [R][C] -> bf16 [C][R] ----------------
__global__ __launch_bounds__(256) void transpose_f32_bf16_k(const float* __restrict__ in,
                                                            u16* __restrict__ out, int R, int C) {
  __shared__ float tile[32][33];
  int bc = blockIdx.x * 32, br = blockIdx.y * 32;
  int tx = threadIdx.x & 31, ty = threadIdx.x >> 5;
#pragma unroll
  for (int p = 0; p < 4; ++p)
    tile[ty + p * 8][tx] = in[(size_t)(br + ty + p * 8) * C + bc + tx];
  __syncthreads();
#pragma unroll
  for (int p = 0; p < 4; ++p)
    out[(size_t)(bc + ty + p * 8) * R + br + tx] = f2bf(tile[tx][ty + p * 8]);
}

// ---------------- GEMM (m97 structure, round-8/13 best): C = A * Bt^T, K=1024, BK=32 --------
// MODE 0: qkv epilogue (bias + fused RoPE + Q pre-scale + scatter to [which][b][h][s][64]);
// MODE 1: out epilogue (bias + fp32 store [m][1024]).
template <int MODE>
__global__ __launch_bounds__(256) void gemm_bt_k(const u16* __restrict__ A,
                                                 const u16* __restrict__ Bt,
                                                 const float* __restrict__ bias,
                                                 const float* __restrict__ cosT,
                                                 const float* __restrict__ sinT,
                                                 void* __restrict__ Cout) {
  __shared__ __align__(16) u16 As[128 * 32];
  __shared__ __align__(16) u16 Bs[128 * 32];
  const int tid = threadIdx.x, lane = tid & 63, w = tid >> 6;
  const int wr = w >> 1, wc = w & 1, g = lane >> 4, c16 = lane & 15;
  const int rowBase = blockIdx.y * 128, colBase = blockIdx.x * 128;
  f32x4 acc[4][4] = {};
  const int e0 = (w * 2 + 0) * 512 + lane * 8;
  const int e1 = (w * 2 + 1) * 512 + lane * 8;
  const u16* Ag0 = A + (size_t)(rowBase + (e0 >> 5)) * 1024 + (e0 & 31);
  const u16* Ag1 = A + (size_t)(rowBase + (e1 >> 5)) * 1024 + (e1 & 31);
  const u16* Bg0 = Bt + (size_t)(colBase + (e0 >> 5)) * 1024 + (e0 & 31);
  const u16* Bg1 = Bt + (size_t)(colBase + (e1 >> 5)) * 1024 + (e1 & 31);
  u16* As0 = As + (w * 2 + 0) * 512;
  u16* As1 = As + (w * 2 + 1) * 512;
  u16* Bs0 = Bs + (w * 2 + 0) * 512;
  u16* Bs1 = Bs + (w * 2 + 1) * 512;
  for (int k0 = 0; k0 < 1024; k0 += 32) {
    __builtin_amdgcn_global_load_lds((const AS1 void*)(Ag0 + k0), (AS3 void*)As0, 16, 0, 0);
    __builtin_amdgcn_global_load_lds((const AS1 void*)(Ag1 + k0), (AS3 void*)As1, 16, 0, 0);
    __builtin_amdgcn_global_load_lds((const AS1 void*)(Bg0 + k0), (AS3 void*)Bs0, 16, 0, 0);
    __builtin_amdgcn_global_load_lds((const AS1 void*)(Bg1 + k0), (AS3 void*)Bs1, 16, 0, 0);
    asm volatile("s_waitcnt vmcnt(0)" ::: "memory");
    __syncthreads();
    short8 af[4], bfr[4];
#pragma unroll
    for (int t = 0; t < 4; ++t)
      af[t] = *(const short8*)(As + ((wr * 64 + t * 16 + c16) * 32 + g * 8));
#pragma unroll
    for (int t = 0; t < 4; ++t)
      bfr[t] = *(const short8*)(Bs + ((wc * 64 + t * 16 + c16) * 32 + g * 8));
#pragma unroll
    for (int i = 0; i < 4; ++i)
#pragma unroll
      for (int j = 0; j < 4; ++j) acc[i][j] = mfma16(af[i], bfr[j], acc[i][j]);
    __syncthreads();
  }
#pragma unroll
  for (int i = 0; i < 4; ++i) {
    int mbase = rowBase + wr * 64 + i * 16 + 4 * g;
#pragma unroll
    for (int j = 0; j < 4; ++j) {
      int n = colBase + wc * 64 + j * 16 + c16;
      float bv = bias[n];
#pragma unroll
      for (int r = 0; r < 4; ++r) {
        float v = acc[i][j][r] + bv;
        int m = mbase + r;
        if (MODE == 0) {
          int which = n >> 10, hh = (n >> 6) & 15, d = n & 63;
          int bb = m >> 11, s = m & 2047;
          float outv = v;
          if (which < 2) {  // fused RoPE (pair element lives in lane^1, same i,j,r)
            float pv = __shfl_xor(v, 1);
            float cc = cosT[(size_t)s * 32 + (d >> 1)];
            float ss = sinT[(size_t)s * 32 + (d >> 1)];
            outv = (d & 1) ? (v * cc + pv * ss) : (v * cc - pv * ss);
            if (which == 0) outv *= 0.18033688f;  // 0.125 * log2(e)
          }
          ((u16*)Cout)[((size_t)(((which * 2 + bb) * 16 + hh) * 2048 + s) << 6) + d] = f2bf(outv);
        } else {
          ((float*)Cout)[(size_t)m * 1024 + n] = v;
        }
      }
    }
  }
}

// ---------------- V [bh][s][64] -> Vt [bh][64][s] (bf16) ----------------
__global__ __launch_bounds__(256) void vtrans_k(const u16* __restrict__ V, u16* __restrict__ Vt) {
  __shared__ u16 t[64][72];
  const int bh = blockIdx.y, s0 = blockIdx.x * 64;
  const u16* src = V + ((size_t)bh << 17);
  u16* dst = Vt + ((size_t)bh << 17);
  const int r = threadIdx.x >> 2, c0 = (threadIdx.x & 3) * 16;
  *(short8*)&t[r][c0] = *(const short8*)(src + (size_t)(s0 + r) * 64 + c0);
  *(short8*)&t[r][c0 + 8] = *(const short8*)(src + (size_t)(s0 + r) * 64 + c0 + 8);
  __syncthreads();
  const int d = threadIdx.x >> 2, sc0 = (threadIdx.x & 3) * 16;
  ushort8 o0, o1;
#pragma unroll
  for (int e = 0; e < 8; ++e) { o0[e] = t[sc0 + e][d]; o1[e] = t[sc0 + 8 + e][d]; }
  *(ushort8*)(dst + (size_t)d * 2048 + s0 + sc0) = o0;
  *(ushort8*)(dst + (size_t)d * 2048 + s0 + sc0 + 8) = o1;
}

// ---------------- Flash attention v10: heavy-macro kv-split, 3 blocks/CU, partial merge ------
// 768 blocks x 4 waves. Per-XCD idx: j=idx&3 (bh slot), u=idx>>2 (0..23):
//   u<8       : whole macro qm=u,        tiles [0, 2u+2)
//   u in 8..15: half 0 of qm=15-(u&7),   tiles [0, qm+1)
//   u in 16..23: half 1 of qm=15-(u&7),  tiles [qm+1, 2qm+2)
// CU triple {2v+2, 16-v, 16-v} = 34 tiles, same bh (K/V L2-shared). Split blocks write
// un-normalized partials (acc bf16, m/l f32) to dead ws regions; merge10_k combines.
__global__ __launch_bounds__(256, 3) void attn10_k(const u16* __restrict__ Qm,
                                                   const u16* __restrict__ Km,
                                                   const u16* __restrict__ Vtm,
                                                   u16* __restrict__ Pacc,
                                                   float* __restrict__ Ml,
                                                   u16* __restrict__ Om) {
  __shared__ __align__(16) u16 KL[2][4096];
  __shared__ __align__(16) u16 VL[2][4096];

  const int tid = threadIdx.x;
  const int lane = tid & 63, w = tid >> 6;
  const int x = blockIdx.x & 7;
  const int idx = blockIdx.x >> 3;                 // 0..95
  const int j = idx & 3, u = idx >> 2;             // u: 0..23
  const int bh = 4 * x + j;
  int qm, t0, t1, half;
  bool split;
  if (u < 8) { qm = u; split = false; half = 0; t0 = 0; t1 = 2 * u + 2; }
  else { split = true; half = (u >= 16); qm = 15 - (u & 7); t0 = half ? (qm + 1) : 0; t1 = t0 + qm + 1; }
  const int b = bh >> 4, hd = bh & 15;
  const int qb = qm * 128 + w * 32;
  const int q32 = lane & 31, hl = lane >> 5;

  const u16* Qp = Qm + ((size_t)bh << 17);
  const u16* Kp = Km + ((size_t)bh << 17);
  const u16* Vtp = Vtm + ((size_t)bh << 17);

  const u16* qrow = Qp + ((size_t)(qb + q32) << 6) + 8 * hl;
  short8 qf[4];
#pragma unroll
  for (int ks = 0; ks < 4; ++ks) qf[ks] = *(const short8*)(qrow + 16 * ks);

  f32x16 acc0 = {}, acc1 = {};
  float m_run = -1e30f, l_run = 0.f;
  const int qg = qb + q32;
  const int rr = w * 8 + (lane >> 3);
  const int sb = (lane & 7) ^ (lane >> 3);
  const int swz = q32 & 7;

  auto stage = [&](int buf, int k0s) {
    u16* kb = &KL[buf][w * 512];
    u16* vb = &VL[buf][w * 512];
    __builtin_amdgcn_global_load_lds(
        (const AS1 void*)(Kp + ((size_t)(k0s + rr) << 6) + sb * 8),
        (AS3 void*)kb, 16, 0, 0);
    __builtin_amdgcn_global_load_lds(
        (const AS1 void*)(Kp + ((size_t)(k0s + rr + 32) << 6) + sb * 8),
        (AS3 void*)(kb + 2048), 16, 0, 0);
    __builtin_amdgcn_global_load_lds(
        (const AS1 void*)(Vtp + ((size_t)rr << 11) + k0s + sb * 8),
        (AS3 void*)vb, 16, 0, 0);
    __builtin_amdgcn_global_load_lds(
        (const AS1 void*)(Vtp + ((size_t)(rr + 32) << 11) + k0s + sb * 8),
        (AS3 void*)(vb + 2048), 16, 0, 0);
  };

  stage(0, 64 * t0);
  asm volatile("s_waitcnt vmcnt(0)" ::: "memory");
  __syncthreads();

  for (int it = t0; it < t1; ++it) {
    const int cur = (it - t0) & 1;
    if (it + 1 < t1) stage(cur ^ 1, 64 * (it + 1));
    const int k0 = 64 * it;

    if (k0 <= qb + 31) {
      const u16* Kb = &KL[cur][0];
      const u16* Vb = &VL[cur][0];

      f32x16 s0 = {}, s1 = {};
      __builtin_amdgcn_s_setprio(1);
#pragma unroll
      for (int ks = 0; ks < 4; ++ks) {
        const int cb = ((2 * ks + hl) ^ swz) * 8;
        short8 kf0 = *(const short8*)(Kb + q32 * 64 + cb);
        short8 kf1 = *(const short8*)(Kb + (32 + q32) * 64 + cb);
        s0 = mfma32(kf0, qf[ks], s0);
        s1 = mfma32(kf1, qf[ks], s1);
      }
      __builtin_amdgcn_s_setprio(0);

      short8 vfa[4], vfb[4];
#pragma unroll
      for (int ks = 0; ks < 4; ++ks) {
        const int cb = ((2 * ks + hl) ^ swz) * 8;
        vfa[ks] = *(const short8*)(Vb + q32 * 64 + cb);
        vfb[ks] = *(const short8*)(Vb + (32 + q32) * 64 + cb);
      }

      if (k0 + 63 > qb) {
#pragma unroll
        for (int r = 0; r < 16; ++r) {
          const int kvl = k0 + (r & 3) + 8 * (r >> 2) + 4 * hl;
          s0[r] = (kvl <= qg) ? s0[r] : -1e30f;
          s1[r] = (kvl + 32 <= qg) ? s1[r] : -1e30f;
        }
      }

      float pmax = s0[0];
#pragma unroll
      for (int r = 1; r < 16; ++r) pmax = fmaxf(pmax, s0[r]);
#pragma unroll
      for (int r = 0; r < 16; ++r) pmax = fmaxf(pmax, s1[r]);
      pmax = fmaxf(pmax, __shfl_xor(pmax, 32));

      if (!__all(pmax <= m_run + 11.5f)) {
        const float mn = fmaxf(m_run, pmax);
        const float alpha = exp2h(m_run - mn);
        l_run *= alpha;
        m_run = mn;
#pragma unroll
        for (int r = 0; r < 16; ++r) {
          const int row = (r & 3) + 8 * (r >> 2) + 4 * hl;
          const float ar = __shfl(alpha, row);
          acc0[r] *= ar; acc1[r] *= ar;
        }
      }

      float rs = 0.f;
#pragma unroll
      for (int r = 0; r < 16; ++r) { s0[r] = exp2h(s0[r] - m_run); rs += s0[r]; }
#pragma unroll
      for (int r = 0; r < 16; ++r) { s1[r] = exp2h(s1[r] - m_run); rs += s1[r]; }
      rs += __shfl_xor(rs, 32);
      l_run += rs;

      short8 pa[4];
#pragma unroll
      for (int t = 0; t < 2; ++t) {
        float p0, p1, p2, p3, p4, p5, p6, p7, p8, p9, pa_, pb_, pc_, pd_, pe_, pf_;
        if (t == 0) {
          p0 = s0[0];  p1 = s0[1];  p2 = s0[2];  p3 = s0[3];
          p4 = s0[4];  p5 = s0[5];  p6 = s0[6];  p7 = s0[7];
          p8 = s0[8];  p9 = s0[9];  pa_ = s0[10]; pb_ = s0[11];
          pc_ = s0[12]; pd_ = s0[13]; pe_ = s0[14]; pf_ = s0[15];
        } else {
          p0 = s1[0];  p1 = s1[1];  p2 = s1[2];  p3 = s1[3];
          p4 = s1[4];  p5 = s1[5];  p6 = s1[6];  p7 = s1[7];
          p8 = s1[8];  p9 = s1[9];  pa_ = s1[10]; pb_ = s1[11];
          pc_ = s1[12]; pd_ = s1[13]; pe_ = s1[14]; pf_ = s1[15];
        }
        const unsigned a0 = cvtpk(p0, p1), a1 = cvtpk(p2, p3);
        const unsigned a2 = cvtpk(p4, p5), a3 = cvtpk(p6, p7);
        const unsigned b0 = cvtpk(p8, p9), b1 = cvtpk(pa_, pb_);
        const unsigned b2 = cvtpk(pc_, pd_), b3 = cvtpk(pe_, pf_);
        const unsigned r0 = __shfl_xor(hl ? a0 : a2, 32);
        const unsigned r1 = __shfl_xor(hl ? a1 : a3, 32);
        pa[2 * t] = hl ? pack4(r0, r1, a2, a3) : pack4(a0, a1, r0, r1);
        const unsigned r2 = __shfl_xor(hl ? b0 : b2, 32);
        const unsigned r3 = __shfl_xor(hl ? b1 : b3, 32);
        pa[2 * t + 1] = hl ? pack4(r2, r3, b2, b3) : pack4(b0, b1, r2, r3);
      }

      __builtin_amdgcn_s_setprio(1);
#pragma unroll
      for (int ks = 0; ks < 4; ++ks) {
        acc0 = mfma32(pa[ks], vfa[ks], acc0);
        acc1 = mfma32(pa[ks], vfb[ks], acc1);
      }
      __builtin_amdgcn_s_setprio(0);
    }

    asm volatile("s_waitcnt vmcnt(0)" ::: "memory");
    __syncthreads();
  }

  if (!split) {
    // whole macro: normalize + store
#pragma unroll
    for (int r = 0; r < 16; ++r) {
      const int row = (r & 3) + 8 * (r >> 2) + 4 * hl;
      const float li = 1.0f / __shfl(l_run, row);
      const int q = qb + row;
      const size_t base = ((size_t)(b * 2048 + q) << 10) + hd * 64 + q32;
      Om[base] = f2bf(acc0[r] * li);
      Om[base + 32] = f2bf(acc1[r] * li);
    }
  } else {
    // partial: un-normalized acc (bf16) + per-row m,l (f32)
    const int slot = half * 256 + bh * 8 + (qm - 8);
    u16* pacc = Pacc + (size_t)slot * 8192;       // [128 rows][64 cols] bf16
#pragma unroll
    for (int r = 0; r < 16; ++r) {
      const int row = (r & 3) + 8 * (r >> 2) + 4 * hl;
      const int rl = w * 32 + row;
      pacc[rl * 64 + q32] = f2bf(acc0[r]);
      pacc[rl * 64 + q32 + 32] = f2bf(acc1[r]);
    }
    if (hl == 0) {
      Ml[(size_t)slot * 128 + w * 32 + q32] = m_run;          // m region
      Ml[65536 + (size_t)slot * 128 + w * 32 + q32] = l_run;  // l region
    }
  }
}

// ---------------- merge split partials -> AttnOut ----------------
__global__ __launch_bounds__(256) void merge10_k(const u16* __restrict__ Pacc,
                                                 const float* __restrict__ Ml,
                                                 u16* __restrict__ Om) {
  const int x = blockIdx.x & 7;
  const int t = blockIdx.x >> 3;                  // 0..31
  const int j = t & 3, qs = t >> 2;               // qs 0..7
  const int bh = 4 * x + j, qm = 8 + qs;
  const int b = bh >> 4, hd = bh & 15;
  const int s0 = bh * 8 + qs, s1 = 256 + s0;
  const u16* a0p = Pacc + (size_t)s0 * 8192;
  const u16* a1p = Pacc + (size_t)s1 * 8192;
#pragma unroll
  for (int k = 0; k < 4; ++k) {
    const int i = threadIdx.x + 256 * k;          // 0..1023 (ushort8 units)
    const int row = i >> 3, co = (i & 7) * 8;
    const float m0 = Ml[(size_t)s0 * 128 + row];
    const float m1 = Ml[(size_t)s1 * 128 + row];
    const float l0 = Ml[65536 + (size_t)s0 * 128 + row];
    const float l1 = Ml[65536 + (size_t)s1 * 128 + row];
    const float M = fmaxf(m0, m1);
    const float e0 = exp2h(m0 - M), e1 = exp2h(m1 - M);
    const float li = 1.0f / (l0 * e0 + l1 * e1);
    const ushort8 A0 = *(const ushort8*)(a0p + row * 64 + co);
    const ushort8 A1 = *(const ushort8*)(a1p + row * 64 + co);
    ushort8 o;
#pragma unroll
    for (int e = 0; e < 8; ++e)
      o[e] = f2bf((b2f(A0[e]) * e0 + b2f(A1[e]) * e1) * li);
    *(ushort8*)(Om + ((size_t)(b * 2048 + qm * 128 + row) << 10) + hd * 64 + co) = o;
  }
}

extern "C" void kernel_launch(void* const* d_in, const int* in_sizes, int n_in,
                              void* d_out, int out_size, void* d_ws, size_t ws_size,
                              hipStream_t stream) {
  const float* x        = (const float*)d_in[0];
  const float* rope_cos = (const float*)d_in[1];
  const float* rope_sin = (const float*)d_in[2];
  const float* Wqkv     = (const float*)d_in[3];
  const float* bqkv     = (const float*)d_in[4];
  const float* Wout     = (const float*)d_in[5];
  const float* bout     = (const float*)d_in[6];
  float* out = (float*)d_out;
  char* ws = (char*)d_ws;

  u16* Xb      = (u16*)(ws);                  //  8,388,608 B : x bf16 (dead after gemm<0> -> Pacc)
  u16* WqkvT   = (u16*)(ws + 8388608);        //  6,291,456 B : Wqkv^T (dead after gemm<0> -> Ml)
  u16* WoutT   = (u16*)(ws + 14680064);       //  2,097,152 B : Wout^T bf16
  u16* QKV     = (u16*)(ws + 16777216);       // 25,165,824 B : [3][2][16][2048][64]
  u16* AttnOut = (u16*)(ws + 41943040);       //  8,388,608 B : [4096][1024] bf16
  u16* Vt      = (u16*)(ws + 50331648);       //  8,388,608 B : [32][64][2048] bf16

  u16* Pacc = (u16*)(ws);                     // reuse Xb region: 2*256*8192*2B = 8,388,608 B
  float* Ml = (float*)(ws + 8388608);         // reuse WqkvT region: 512 KB (m then l)

  cvt_f32_bf16_k<<<dim3(2048), dim3(256), 0, stream>>>(x, Xb, 524288);
  transpose_f32_bf16_k<<<dim3(96, 32), dim3(256), 0, stream>>>(Wqkv, WqkvT, 1024, 3072);
  transpose_f32_bf16_k<<<dim3(32, 32), dim3(256), 0, stream>>>(Wout, WoutT, 1024, 1024);

  // QKV projection with fused bias + RoPE + Q pre-scale + scatter
  gemm_bt_k<0><<<dim3(24, 32), dim3(256), 0, stream>>>(Xb, WqkvT, bqkv, rope_cos, rope_sin,
                                                       (void*)QKV);

  u16* Qw = QKV;
  u16* Kw = QKV + (size_t)4194304;
  u16* Vw = QKV + (size_t)8388608;
  vtrans_k<<<dim3(32, 32), dim3(256), 0, stream>>>(Vw, Vt);

  attn10_k<<<dim3(768), dim3(256), 0, stream>>>(Qw, Kw, Vt, Pacc, Ml, AttnOut);
  merge10_k<<<dim3(256), dim3(256), 0, stream>>>(Pacc, Ml, AttnOut);

  gemm_bt_k<1><<<dim3(8, 32), dim3(256), 0, stream>>>(AttnOut, WoutT, bout, nullptr, nullptr, out);
}